// Round 9
// baseline (70.513 us; speedup 1.0000x reference)
//
#include <hip/hip_runtime.h>
#include <stdint.h>

#define Bn 8
#define Nn 2000
#define Cc 81
#define META_STRIDE (12 + Cc)
#define MAXI 100
#define MINCONF 0.7f
#define NMSTHR 0.3f
#define NPAD 2048
#define PB_ROIS 128  // ROIs per k_prep block (16000 / 128 = 125 blocks)
#define PSTRIDE 83   // LDS row stride (81 + 2 pad)

// map float to monotonically ordered uint (descending float == descending uint)
__device__ __forceinline__ uint32_t ford(float f) {
    uint32_t u = __float_as_uint(f);
    return (u & 0x80000000u) ? ~u : (u | 0x80000000u);
}

__device__ __forceinline__ unsigned long long shflx64(unsigned long long v, int lx) {
    unsigned int lo = (unsigned int)v, hi = (unsigned int)(v >> 32);
    lo = (unsigned int)__shfl_xor((int)lo, lx, 64);
    hi = (unsigned int)__shfl_xor((int)hi, lx, 64);
    return ((unsigned long long)hi << 32) | lo;
}

// ---------------- Kernel 1: LDS-staged argmax, delta apply, clip, sort key --
// (unchanged — passed with absmax 0.0)
__global__ void __launch_bounds__(256)
k_prep(const float* __restrict__ rois,
       const float* __restrict__ probs,
       const float* __restrict__ bbox,
       const float* __restrict__ meta,
       float* __restrict__ refined,
       float* __restrict__ score,
       int* __restrict__ cls,
       unsigned long long* __restrict__ keys) {
    __shared__ float sp[PB_ROIS * PSTRIDE];   // 42.5 KB
    int tid  = threadIdx.x;
    int base = blockIdx.x * PB_ROIS;

    const float* gp = probs + (size_t)base * Cc;
    const int total = PB_ROIS * Cc;           // 10368
    int r = tid / Cc, c = tid - r * Cc;
    for (int idx = tid; idx < total; idx += 256) {
        sp[r * PSTRIDE + c] = gp[idx];
        r += 3; c += 13;                      // 256 = 3*81 + 13
        if (c >= Cc) { c -= Cc; r += 1; }
    }
    __syncthreads();

    int row  = tid >> 1;
    int half = tid & 1;
    const float* sr = sp + row * PSTRIDE;
    int   c0 = half ? 41 : 0;
    int   c1 = half ? Cc : 41;
    float v  = sr[c0];
    int   cb = c0;
    for (int cc2 = c0 + 1; cc2 < c1; ++cc2) {
        float x = sr[cc2];
        if (x > v) { v = x; cb = cc2; }       // first max wins within half
    }
    float vo = __shfl_xor(v, 1, 64);
    int   co = __shfl_xor(cb, 1, 64);
    float vA = half ? vo : v;   int cA = half ? co : cb;   // low half
    float vB = half ? v  : vo;  int cB = half ? cb : co;   // high half
    float sbest;  int cbest;
    if (vB > vA) { sbest = vB; cbest = cB; }  // tie -> low half (lower index)
    else         { sbest = vA; cbest = cA; }

    if (half) return;
    int t = base + row;

    float4 d4 = reinterpret_cast<const float4*>(bbox)[(size_t)t * Cc + cbest];
    float dy = d4.x * 0.1f, dx = d4.y * 0.1f, dh = d4.z * 0.2f, dw = d4.w * 0.2f;

    float4 r4 = reinterpret_cast<const float4*>(rois)[t];
    float y1 = r4.x, x1 = r4.y, y2 = r4.z, x2 = r4.w;
    float h = y2 - y1, w = x2 - x1;
    float cy = y1 + 0.5f * h + dy * h;
    float cx = x1 + 0.5f * w + dx * w;
    h = h * expf(dh);
    w = w * expf(dw);
    float ny1 = cy - 0.5f * h, nx1 = cx - 0.5f * w;
    float ny2 = cy + 0.5f * h, nx2 = cx + 0.5f * w;

    int b = t / Nn;
    float sy = meta[4] - 1.0f, sx = meta[5] - 1.0f;
    const float* mb = meta + (size_t)b * META_STRIDE;
    float wy1 = mb[7] / sy;
    float wx1 = mb[8] / sx;
    float wy2 = (mb[9]  - 1.0f) / sy;
    float wx2 = (mb[10] - 1.0f) / sx;

    ny1 = fminf(fmaxf(ny1, wy1), wy2);
    nx1 = fminf(fmaxf(nx1, wx1), wx2);
    ny2 = fminf(fmaxf(ny2, wy1), wy2);
    nx2 = fminf(fmaxf(nx2, wx1), wx2);

    reinterpret_cast<float4*>(refined)[t] = float4{ny1, nx1, ny2, nx2};
    score[t] = sbest;
    cls[t]   = cbest;

    int i = t - b * Nn;
    bool valid = (cbest > 0) && (sbest >= MINCONF);
    float ks = valid ? sbest : -1.0f;
    keys[t] = ((unsigned long long)ford(ks) << 32) |
              (unsigned long long)(0xFFFFFFFFu - (uint32_t)i);
}

// ---------------- Kernel 2: fused register-bitonic sort + pipelined NMS -----
// Sort identical to round 8. NMS: intra 64x64 masks precomputed for ALL blocks
// upfront (shfl-based, one barrier); main loop is 1 barrier/iteration: waves
// 1..15 compute ext-suppression of block t vs klist[0..P_{t-2}) (published via
// sKpub double-buffer) WHILE wave 0 resolves block t-1 (ext from extbuf
// double-buffer + delta IoUs vs boxes kept in block t-2 + precomputed intra).
// klist appends (indices >= P_{t-2}) are disjoint from concurrent reads.
__global__ void __launch_bounds__(1024, 1)
k_batch(const unsigned long long* __restrict__ keys,
        const float* __restrict__ refined,
        const float* __restrict__ score,
        const int* __restrict__ cls,
        float* __restrict__ out) {
    __shared__ unsigned long long sk[NPAD];      // 16 KB
    __shared__ float4 sboxL[Nn];                 // 32 KB (sorted offset boxes)
    __shared__ unsigned long long intraM[NPAD];  // 16 KB (intra-block rows)
    __shared__ unsigned long long extbuf[2][16]; // double-buffered ext ballots
    __shared__ int klist[128];                   // kept sorted positions
    __shared__ int sKpub[2];                     // published kept count (2-slot)
    __shared__ int sV, sNk, sDone;

    int b = blockIdx.x, tid = threadIdx.x;
    int wid = tid >> 6, lane = tid & 63;
    int e0 = tid << 1;

    // ---- load pair into registers ----
    const unsigned long long* kb = keys + (size_t)b * Nn;
    unsigned long long a  = (e0     < Nn) ? kb[e0]     : 0ull;
    unsigned long long bv = (e0 + 1 < Nn) ? kb[e0 + 1] : 0ull;
    if (tid == 0) { sV = 0; sNk = 0; sDone = 0; sKpub[0] = 0; sKpub[1] = 0; }

    // ---- phase A: k = 2..128 entirely in registers ----
    for (int k = 2; k <= 128; k <<= 1) {
        bool desc = ((e0 & k) == 0);
        for (int j = k >> 1; j >= 2; j >>= 1) {
            int lx = j >> 1;
            bool keepmax = (desc == ((lane & lx) == 0));
            unsigned long long oa = shflx64(a, lx);
            unsigned long long ob = shflx64(bv, lx);
            a  = keepmax ? (a  > oa ? a  : oa) : (a  < oa ? a  : oa);
            bv = keepmax ? (bv > ob ? bv : ob) : (bv < ob ? bv : ob);
        }
        bool sw = desc ? (a < bv) : (a > bv);
        if (sw) { unsigned long long t2 = a; a = bv; bv = t2; }
    }
    sk[e0] = a; sk[e0 + 1] = bv;
    __syncthreads();

    // ---- phase B: k = 256..2048 ----
    for (int k = 256; k <= NPAD; k <<= 1) {
        for (int j = k >> 1; j >= 128; j >>= 1) {
            #pragma unroll
            for (int rep = 0; rep < 2; ++rep) {
                int t = tid + (rep << 10);
                int ixj = t ^ j;
                if (ixj > t) {
                    unsigned long long x = sk[t], y = sk[ixj];
                    bool desc = ((t & k) == 0);
                    if (desc ? (x < y) : (x > y)) { sk[t] = y; sk[ixj] = x; }
                }
            }
            __syncthreads();
        }
        a = sk[e0]; bv = sk[e0 + 1];
        bool desc = ((e0 & k) == 0);
        #pragma unroll
        for (int lx = 32; lx >= 1; lx >>= 1) {
            bool keepmax = (desc == ((lane & lx) == 0));
            unsigned long long oa = shflx64(a, lx);
            unsigned long long ob = shflx64(bv, lx);
            a  = keepmax ? (a  > oa ? a  : oa) : (a  < oa ? a  : oa);
            bv = keepmax ? (bv > ob ? bv : ob) : (bv < ob ? bv : ob);
        }
        bool sw = desc ? (a < bv) : (a > bv);
        if (sw) { unsigned long long t2 = a; a = bv; bv = t2; }
        sk[e0] = a; sk[e0 + 1] = bv;
        __syncthreads();
    }

    // ---- valid prefix length V ----
    for (int t = tid; t < Nn; t += 1024) {
        bool v0 = (sk[t] >> 63) != 0ull;
        bool v1 = (t + 1 < Nn) ? ((sk[t + 1] >> 63) != 0ull) : false;
        if (v0 && !v1) sV = t + 1;            // single boundary -> single writer
    }
    __syncthreads();
    int V = sV;

    // ---- sorted offset-boxes into LDS ----
    for (int t = tid; t < V; t += 1024) {
        uint32_t oi = 0xFFFFFFFFu - (uint32_t)(sk[t] & 0xFFFFFFFFull);
        int gi = b * Nn + (int)oi;
        float off = 4.0f * (float)cls[gi];    // CLASS_OFFSET * class_id
        float4 rf = reinterpret_cast<const float4*>(refined)[gi];
        sboxL[t] = float4{rf.x + off, rf.y + off, rf.z + off, rf.w + off};
    }
    __syncthreads();

    // ---- precompute intra-block 64x64 masks (one wave per block, shfl) ----
    int nblocks = (V + 63) >> 6;
    for (int tb = wid; tb < nblocks; tb += 16) {
        int base = tb << 6;
        int pos = base + lane;
        float4 cb = (pos < V) ? sboxL[pos] : float4{0.f, 0.f, 0.f, 0.f};
        float a2 = (cb.z - cb.x) * (cb.w - cb.y);
        int nb = V - base; if (nb > 64) nb = 64;
        for (int r = 0; r < nb; ++r) {
            float rx = __shfl(cb.x, r, 64);
            float ry = __shfl(cb.y, r, 64);
            float rz = __shfl(cb.z, r, 64);
            float rw = __shfl(cb.w, r, 64);
            float ar = (rz - rx) * (rw - ry);
            bool sup = false;
            if (lane > r && pos < V) {
                float iy = fmaxf(0.0f, fminf(rz, cb.z) - fmaxf(rx, cb.x));
                float ix = fmaxf(0.0f, fminf(rw, cb.w) - fmaxf(ry, cb.y));
                float inter = iy * ix;
                float iou = inter / (ar + a2 - inter + 1e-12f);
                sup = iou > NMSTHR;
            }
            unsigned long long ball = __ballot(sup);
            if (lane == 0) intraM[base + r] = ball;
        }
    }
    __syncthreads();

    // ---- pipelined NMS: 1 barrier per iteration ----
    int prevP = 0, lastP = 0;                 // wave-0 uniform registers
    for (int t = 0; t <= nblocks; ++t) {
        if (sDone) break;                     // uniform (post-barrier read)
        if (wid != 0) {
            if (t < nblocks) {                // ext of block t vs published kept
                int base = t << 6;
                int nb = V - base; if (nb > 64) nb = 64;
                float4 cb = (lane < nb) ? sboxL[base + lane]
                                        : float4{0.f, 0.f, 0.f, 0.f};
                float a2 = (cb.z - cb.x) * (cb.w - cb.y);
                int Kold = sKpub[t & 1];      // = P_{t-2}
                bool supext = false;
                for (int k = wid - 1; k < Kold; k += 15) {
                    float4 kbx = sboxL[klist[k]];
                    float ar = (kbx.z - kbx.x) * (kbx.w - kbx.y);
                    float iy = fmaxf(0.0f, fminf(kbx.z, cb.z) - fmaxf(kbx.x, cb.x));
                    float ix = fmaxf(0.0f, fminf(kbx.w, cb.w) - fmaxf(kbx.y, cb.y));
                    float inter = iy * ix;
                    float iou = inter / (ar + a2 - inter + 1e-12f);
                    supext |= (lane < nb) && (iou > NMSTHR);
                }
                unsigned long long bw = __ballot(supext);
                if (lane == 0) extbuf[t & 1][wid] = bw;
            }
        } else {
            int bt = t - 1;                   // wave 0: resolve block t-1
            if (bt >= 0 && bt < nblocks) {
                int base = bt << 6;
                int nb = V - base; if (nb > 64) nb = 64;

                // gather ext ballots from iter t-1 (slots 1..15)
                unsigned long long e =
                    (lane >= 1 && lane < 16) ? extbuf[bt & 1][lane] : 0ull;
                #pragma unroll
                for (int m = 32; m >= 1; m >>= 1) e |= shflx64(e, m);

                // delta: boxes kept in block bt-1 (indices [prevP, lastP))
                int dn = lastP - prevP;
                float4 cbr = (lane < nb) ? sboxL[base + lane]
                                         : float4{0.f, 0.f, 0.f, 0.f};
                float a2r = (cbr.z - cbr.x) * (cbr.w - cbr.y);
                float4 kb4 = float4{0.f, 0.f, 0.f, 0.f};
                if (lane < dn) kb4 = sboxL[klist[prevP + lane]];
                for (int d = 0; d < dn; ++d) {
                    float kx = __shfl(kb4.x, d, 64);
                    float ky = __shfl(kb4.y, d, 64);
                    float kz = __shfl(kb4.z, d, 64);
                    float kw = __shfl(kb4.w, d, 64);
                    float ar = (kz - kx) * (kw - ky);
                    float iy = fmaxf(0.0f, fminf(kz, cbr.z) - fmaxf(kx, cbr.x));
                    float ix = fmaxf(0.0f, fminf(kw, cbr.w) - fmaxf(ky, cbr.y));
                    float inter = iy * ix;
                    float iou = inter / (ar + a2r - inter + 1e-12f);
                    e |= __ballot((lane < nb) && (iou > NMSTHR));
                }

                unsigned long long myintra = intraM[base + lane];
                bool alive = (lane < nb) && !((e >> lane) & 1ull);
                unsigned long long candm = __ballot(alive);
                int nk = lastP;
                while (candm) {               // one iteration per KEPT box
                    int i = __builtin_ctzll(candm);
                    if (lane == 0) klist[nk] = base + i;
                    ++nk;
                    if (nk >= MAXI) { if (lane == 0) sDone = 1; break; }
                    unsigned long long rowi = __shfl(myintra, i, 64);
                    alive = alive && !((rowi >> lane) & 1ull);
                    candm = __ballot(alive) & ~((2ull << i) - 1ull);
                }
                prevP = lastP; lastP = nk;
                if (lane == 0) sKpub[(t + 1) & 1] = nk;  // publish P_{t-1}
            }
            if (t == nblocks && lane == 0) sNk = lastP;
        }
        __syncthreads();
    }
    if (sDone && wid == 0 && lane == 0) sNk = lastP;  // capped case
    __syncthreads();

    // ---- emit first min(100, kept) in sorted order; zero-fill tail ----
    int ne = sNk < MAXI ? sNk : MAXI;
    for (int r = tid; r < ne; r += 1024) {
        int pos = klist[r];
        uint32_t oi = 0xFFFFFFFFu - (uint32_t)(sk[pos] & 0xFFFFFFFFull);
        int gi = b * Nn + (int)oi;
        float4 rf = reinterpret_cast<const float4*>(refined)[gi];
        float* orow = out + ((size_t)b * MAXI + r) * 6;
        orow[0] = rf.x;
        orow[1] = rf.y;
        orow[2] = rf.z;
        orow[3] = rf.w;
        orow[4] = (float)cls[gi];
        orow[5] = score[gi];
    }
    for (int tt = ne * 6 + tid; tt < MAXI * 6; tt += 1024)
        out[(size_t)b * MAXI * 6 + tt] = 0.0f;
}

// ---------------- launch ----------------------------------------------------
extern "C" void kernel_launch(void* const* d_in, const int* in_sizes, int n_in,
                              void* d_out, int out_size, void* d_ws, size_t ws_size,
                              hipStream_t stream) {
    const float* rois  = (const float*)d_in[0];
    const float* probs = (const float*)d_in[1];
    const float* bbox  = (const float*)d_in[2];
    const float* meta  = (const float*)d_in[3];
    float* out = (float*)d_out;

    const int BN = Bn * Nn;
    char* ws = (char*)d_ws;
    size_t off = 0;
    auto alloc = [&](size_t bytes) {
        void* p = ws + off;
        off += (bytes + 255) & ~(size_t)255;
        return p;
    };
    float*              refined = (float*)              alloc((size_t)BN * 4 * sizeof(float));
    float*              score   = (float*)              alloc((size_t)BN * sizeof(float));
    int*                cls     = (int*)                alloc((size_t)BN * sizeof(int));
    unsigned long long* keys    = (unsigned long long*) alloc((size_t)BN * sizeof(unsigned long long));
    (void)ws_size; (void)in_sizes; (void)n_in; (void)out_size;

    k_prep<<<BN / PB_ROIS, 256, 0, stream>>>(rois, probs, bbox, meta,
                                             refined, score, cls, keys);
    k_batch<<<Bn, 1024, 0, stream>>>(keys, refined, score, cls, out);
}

// Round 10
// 55.748 us; speedup vs baseline: 1.2649x; 1.2649x over previous
//
#include <hip/hip_runtime.h>
#include <stdint.h>

#define Bn 8
#define Nn 2000
#define Cc 81
#define META_STRIDE (12 + Cc)
#define MAXI 100
#define MINCONF 0.7f
#define NMSTHR 0.3f
#define NPAD 2048
#define PB_ROIS 128  // ROIs per k_prep block (16000 / 128 = 125 blocks)
#define PSTRIDE 83   // LDS row stride (81 + 2 pad)
#define KCAP 104     // per-class kept-index capacity (total kept <= 100)

// map float to monotonically ordered uint (descending float == descending uint)
__device__ __forceinline__ uint32_t ford(float f) {
    uint32_t u = __float_as_uint(f);
    return (u & 0x80000000u) ? ~u : (u | 0x80000000u);
}

__device__ __forceinline__ unsigned long long shflx64(unsigned long long v, int lx) {
    unsigned int lo = (unsigned int)v, hi = (unsigned int)(v >> 32);
    lo = (unsigned int)__shfl_xor((int)lo, lx, 64);
    hi = (unsigned int)__shfl_xor((int)hi, lx, 64);
    return ((unsigned long long)hi << 32) | lo;
}

// ---------------- Kernel 1: LDS-staged argmax, delta apply, clip, sort key --
// (unchanged — passed with absmax 0.0)
__global__ void __launch_bounds__(256)
k_prep(const float* __restrict__ rois,
       const float* __restrict__ probs,
       const float* __restrict__ bbox,
       const float* __restrict__ meta,
       float* __restrict__ refined,
       float* __restrict__ score,
       int* __restrict__ cls,
       unsigned long long* __restrict__ keys) {
    __shared__ float sp[PB_ROIS * PSTRIDE];   // 42.5 KB
    int tid  = threadIdx.x;
    int base = blockIdx.x * PB_ROIS;

    const float* gp = probs + (size_t)base * Cc;
    const int total = PB_ROIS * Cc;           // 10368
    int r = tid / Cc, c = tid - r * Cc;
    for (int idx = tid; idx < total; idx += 256) {
        sp[r * PSTRIDE + c] = gp[idx];
        r += 3; c += 13;                      // 256 = 3*81 + 13
        if (c >= Cc) { c -= Cc; r += 1; }
    }
    __syncthreads();

    int row  = tid >> 1;
    int half = tid & 1;
    const float* sr = sp + row * PSTRIDE;
    int   c0 = half ? 41 : 0;
    int   c1 = half ? Cc : 41;
    float v  = sr[c0];
    int   cb = c0;
    for (int cc2 = c0 + 1; cc2 < c1; ++cc2) {
        float x = sr[cc2];
        if (x > v) { v = x; cb = cc2; }       // first max wins within half
    }
    float vo = __shfl_xor(v, 1, 64);
    int   co = __shfl_xor(cb, 1, 64);
    float vA = half ? vo : v;   int cA = half ? co : cb;   // low half
    float vB = half ? v  : vo;  int cB = half ? cb : co;   // high half
    float sbest;  int cbest;
    if (vB > vA) { sbest = vB; cbest = cB; }  // tie -> low half (lower index)
    else         { sbest = vA; cbest = cA; }

    if (half) return;
    int t = base + row;

    float4 d4 = reinterpret_cast<const float4*>(bbox)[(size_t)t * Cc + cbest];
    float dy = d4.x * 0.1f, dx = d4.y * 0.1f, dh = d4.z * 0.2f, dw = d4.w * 0.2f;

    float4 r4 = reinterpret_cast<const float4*>(rois)[t];
    float y1 = r4.x, x1 = r4.y, y2 = r4.z, x2 = r4.w;
    float h = y2 - y1, w = x2 - x1;
    float cy = y1 + 0.5f * h + dy * h;
    float cx = x1 + 0.5f * w + dx * w;
    h = h * expf(dh);
    w = w * expf(dw);
    float ny1 = cy - 0.5f * h, nx1 = cx - 0.5f * w;
    float ny2 = cy + 0.5f * h, nx2 = cx + 0.5f * w;

    int b = t / Nn;
    float sy = meta[4] - 1.0f, sx = meta[5] - 1.0f;
    const float* mb = meta + (size_t)b * META_STRIDE;
    float wy1 = mb[7] / sy;
    float wx1 = mb[8] / sx;
    float wy2 = (mb[9]  - 1.0f) / sy;
    float wx2 = (mb[10] - 1.0f) / sx;

    ny1 = fminf(fmaxf(ny1, wy1), wy2);
    nx1 = fminf(fmaxf(nx1, wx1), wx2);
    ny2 = fminf(fmaxf(ny2, wy1), wy2);
    nx2 = fminf(fmaxf(nx2, wx1), wx2);

    reinterpret_cast<float4*>(refined)[t] = float4{ny1, nx1, ny2, nx2};
    score[t] = sbest;
    cls[t]   = cbest;

    int i = t - b * Nn;
    bool valid = (cbest > 0) && (sbest >= MINCONF);
    float ks = valid ? sbest : -1.0f;
    keys[t] = ((unsigned long long)ford(ks) << 32) |
              (unsigned long long)(0xFFFFFFFFu - (uint32_t)i);
}

// ---------------- Kernel 2: register-bitonic sort + single-wave bucket NMS --
// Sort identical to round 8 (verified). NMS: since classes are offset by 4,
// cross-class IoU is EXACTLY 0 -> suppression is same-class only. Kept boxes
// are bucketed per class (kcnt/kidx in LDS); each candidate lane checks only
// its own class's kept boxes (~1.3 avg). One wave runs the whole greedy loop
// with ZERO barriers; intra-block suppression via __shfl box broadcast.
__global__ void __launch_bounds__(1024, 1)
k_batch(const unsigned long long* __restrict__ keys,
        const float* __restrict__ refined,
        const float* __restrict__ score,
        const int* __restrict__ cls,
        float* __restrict__ out) {
    __shared__ unsigned long long sk[NPAD];    // 16 KB
    __shared__ float4 sboxL[Nn];               // 32 KB (sorted offset boxes)
    __shared__ unsigned short scls[Nn];        // 4 KB  (sorted classes)
    __shared__ unsigned short kidx[Cc * KCAP]; // 16.8 KB (per-class kept pos)
    __shared__ int kcnt[Cc];                   // per-class kept count
    __shared__ int klist[128];                 // kept sorted positions
    __shared__ int sV, sNk;

    int b = blockIdx.x, tid = threadIdx.x;
    int wid = tid >> 6, lane = tid & 63;
    int e0 = tid << 1;

    // ---- load pair into registers (16B coalesced per lane) ----
    const unsigned long long* kb = keys + (size_t)b * Nn;
    unsigned long long a  = (e0     < Nn) ? kb[e0]     : 0ull;
    unsigned long long bv = (e0 + 1 < Nn) ? kb[e0 + 1] : 0ull;
    if (tid == 0) { sV = 0; sNk = 0; }
    if (tid < Cc) kcnt[tid] = 0;

    // ---- phase A: k = 2..128 entirely in registers (no barriers) ----
    for (int k = 2; k <= 128; k <<= 1) {
        bool desc = ((e0 & k) == 0);
        for (int j = k >> 1; j >= 2; j >>= 1) {
            int lx = j >> 1;
            bool keepmax = (desc == ((lane & lx) == 0));
            unsigned long long oa = shflx64(a, lx);
            unsigned long long ob = shflx64(bv, lx);
            a  = keepmax ? (a  > oa ? a  : oa) : (a  < oa ? a  : oa);
            bv = keepmax ? (bv > ob ? bv : ob) : (bv < ob ? bv : ob);
        }
        bool sw = desc ? (a < bv) : (a > bv);
        if (sw) { unsigned long long t2 = a; a = bv; bv = t2; }
    }
    sk[e0] = a; sk[e0 + 1] = bv;
    __syncthreads();

    // ---- phase B: k = 256..2048; LDS for j>=128, register pass for j<=64 --
    for (int k = 256; k <= NPAD; k <<= 1) {
        for (int j = k >> 1; j >= 128; j >>= 1) {
            #pragma unroll
            for (int rep = 0; rep < 2; ++rep) {
                int t = tid + (rep << 10);
                int ixj = t ^ j;
                if (ixj > t) {
                    unsigned long long x = sk[t], y = sk[ixj];
                    bool desc = ((t & k) == 0);
                    if (desc ? (x < y) : (x > y)) { sk[t] = y; sk[ixj] = x; }
                }
            }
            __syncthreads();
        }
        a = sk[e0]; bv = sk[e0 + 1];
        bool desc = ((e0 & k) == 0);
        #pragma unroll
        for (int lx = 32; lx >= 1; lx >>= 1) {
            bool keepmax = (desc == ((lane & lx) == 0));
            unsigned long long oa = shflx64(a, lx);
            unsigned long long ob = shflx64(bv, lx);
            a  = keepmax ? (a  > oa ? a  : oa) : (a  < oa ? a  : oa);
            bv = keepmax ? (bv > ob ? bv : ob) : (bv < ob ? bv : ob);
        }
        bool sw = desc ? (a < bv) : (a > bv);
        if (sw) { unsigned long long t2 = a; a = bv; bv = t2; }
        sk[e0] = a; sk[e0 + 1] = bv;
        __syncthreads();
    }

    // ---- valid prefix length V ----
    for (int t = tid; t < Nn; t += 1024) {
        bool v0 = (sk[t] >> 63) != 0ull;
        bool v1 = (t + 1 < Nn) ? ((sk[t + 1] >> 63) != 0ull) : false;
        if (v0 && !v1) sV = t + 1;            // single boundary -> single writer
    }
    __syncthreads();
    int V = sV;

    // ---- sorted offset-boxes + classes into LDS ----
    for (int t = tid; t < V; t += 1024) {
        uint32_t oi = 0xFFFFFFFFu - (uint32_t)(sk[t] & 0xFFFFFFFFull);
        int gi = b * Nn + (int)oi;
        int c  = cls[gi];
        float off = 4.0f * (float)c;          // CLASS_OFFSET * class_id
        float4 rf = reinterpret_cast<const float4*>(refined)[gi];
        sboxL[t] = float4{rf.x + off, rf.y + off, rf.z + off, rf.w + off};
        scls[t]  = (unsigned short)c;
    }
    __syncthreads();

    // ---- single-wave greedy NMS (zero barriers inside) ----
    if (wid == 0) {
        int nblocks = (V + 63) >> 6;
        int nk = 0;
        bool done = false;
        for (int t = 0; t < nblocks && !done; ++t) {
            int base = t << 6;
            int nb = V - base; if (nb > 64) nb = 64;
            int pos = base + lane;
            float4 cb = (lane < nb) ? sboxL[pos] : float4{0.f, 0.f, 0.f, 0.f};
            int   myc = (lane < nb) ? (int)scls[pos] : 0;
            float a2  = (cb.z - cb.x) * (cb.w - cb.y);

            // ext: test against kept boxes of MY class only (exact: cross-
            // class IoU == 0 because class windows are >=3 apart)
            bool sup = false;
            int cnt = (lane < nb) ? kcnt[myc] : 0;
            for (int s = 0; s < cnt; ++s) {
                int ki = (int)kidx[myc * KCAP + s];
                float4 kbx = sboxL[ki];
                float ar = (kbx.z - kbx.x) * (kbx.w - kbx.y);
                float iy = fmaxf(0.0f, fminf(kbx.z, cb.z) - fmaxf(kbx.x, cb.x));
                float ix = fmaxf(0.0f, fminf(kbx.w, cb.w) - fmaxf(kbx.y, cb.y));
                float inter = iy * ix;
                float iou = inter / (ar + a2 - inter + 1e-12f);
                sup |= iou > NMSTHR;
            }

            bool alive = (lane < nb) && !sup;
            unsigned long long candm = __ballot(alive);
            while (candm) {                    // one iteration per KEPT box
                int i = __builtin_ctzll(candm);
                int ic = __shfl(myc, i, 64);
                if (lane == 0) {
                    klist[nk] = base + i;
                    int cc2 = kcnt[ic];
                    kidx[ic * KCAP + cc2] = (unsigned short)(base + i);
                    kcnt[ic] = cc2 + 1;
                }
                ++nk;
                if (nk >= MAXI) { done = true; break; }

                // intra: suppress later lanes via shfl'd box of i (exact)
                float kx = __shfl(cb.x, i, 64);
                float ky = __shfl(cb.y, i, 64);
                float kz = __shfl(cb.z, i, 64);
                float kw = __shfl(cb.w, i, 64);
                float ar = (kz - kx) * (kw - ky);
                float iy = fmaxf(0.0f, fminf(kz, cb.z) - fmaxf(kx, cb.x));
                float ix = fmaxf(0.0f, fminf(kw, cb.w) - fmaxf(ky, cb.y));
                float inter = iy * ix;
                float iou = inter / (ar + a2 - inter + 1e-12f);
                alive = alive && !(iou > NMSTHR);
                candm = __ballot(alive) & ~((2ull << i) - 1ull);
            }
        }
        if (lane == 0) sNk = nk;
    }
    __syncthreads();

    // ---- emit first min(100, kept) in sorted order; zero-fill tail ----
    int ne = sNk < MAXI ? sNk : MAXI;
    for (int r = tid; r < ne; r += 1024) {
        int pos = klist[r];
        uint32_t oi = 0xFFFFFFFFu - (uint32_t)(sk[pos] & 0xFFFFFFFFull);
        int gi = b * Nn + (int)oi;
        float4 rf = reinterpret_cast<const float4*>(refined)[gi];
        float* orow = out + ((size_t)b * MAXI + r) * 6;
        orow[0] = rf.x;
        orow[1] = rf.y;
        orow[2] = rf.z;
        orow[3] = rf.w;
        orow[4] = (float)cls[gi];
        orow[5] = score[gi];
    }
    for (int tt = ne * 6 + tid; tt < MAXI * 6; tt += 1024)
        out[(size_t)b * MAXI * 6 + tt] = 0.0f;
}

// ---------------- launch ----------------------------------------------------
extern "C" void kernel_launch(void* const* d_in, const int* in_sizes, int n_in,
                              void* d_out, int out_size, void* d_ws, size_t ws_size,
                              hipStream_t stream) {
    const float* rois  = (const float*)d_in[0];
    const float* probs = (const float*)d_in[1];
    const float* bbox  = (const float*)d_in[2];
    const float* meta  = (const float*)d_in[3];
    float* out = (float*)d_out;

    const int BN = Bn * Nn;
    char* ws = (char*)d_ws;
    size_t off = 0;
    auto alloc = [&](size_t bytes) {
        void* p = ws + off;
        off += (bytes + 255) & ~(size_t)255;
        return p;
    };
    float*              refined = (float*)              alloc((size_t)BN * 4 * sizeof(float));
    float*              score   = (float*)              alloc((size_t)BN * sizeof(float));
    int*                cls     = (int*)                alloc((size_t)BN * sizeof(int));
    unsigned long long* keys    = (unsigned long long*) alloc((size_t)BN * sizeof(unsigned long long));
    (void)ws_size; (void)in_sizes; (void)n_in; (void)out_size;

    k_prep<<<BN / PB_ROIS, 256, 0, stream>>>(rois, probs, bbox, meta,
                                             refined, score, cls, keys);
    k_batch<<<Bn, 1024, 0, stream>>>(keys, refined, score, cls, out);
}